// Round 1
// baseline (1426.326 us; speedup 1.0000x reference)
//
#include <hip/hip_runtime.h>

typedef __bf16 bf16x8 __attribute__((ext_vector_type(8)));
typedef float f32x4 __attribute__((ext_vector_type(4)));

__device__ __forceinline__ unsigned short f2b(float f) {
  union { float f; unsigned u; } v; v.f = f;
  unsigned u = v.u;
  u = (u + 0x7fffu + ((u >> 16) & 1u)) >> 16;
  return (unsigned short)u;
}
__device__ __forceinline__ float b2f(unsigned short b) {
  union { unsigned u; float f; } v; v.u = ((unsigned)b) << 16;
  return v.f;
}
__device__ __forceinline__ void lds_load16(void* lds, const void* g) {
  __builtin_amdgcn_global_load_lds(
      (const __attribute__((address_space(1))) unsigned int*)g,
      (__attribute__((address_space(3))) unsigned int*)lds, 16, 0, 0);
}

// ---------------- kernel 1: x fp32 -> bf16 (131072 x 200) ----------------
__global__ __launch_bounds__(256) void cvt_x_kernel(const float* __restrict__ x,
                                                    unsigned short* __restrict__ xb) {
  size_t i = (size_t)blockIdx.x * 256 + threadIdx.x;  // chunk of 8 elements
  const float4* xp = (const float4*)(x + i * 8);
  float4 a = xp[0], b = xp[1];
  uint4 o;
  o.x = (unsigned)f2b(a.x) | ((unsigned)f2b(a.y) << 16);
  o.y = (unsigned)f2b(a.z) | ((unsigned)f2b(a.w) << 16);
  o.z = (unsigned)f2b(b.x) | ((unsigned)f2b(b.y) << 16);
  o.w = (unsigned)f2b(b.z) | ((unsigned)f2b(b.w) << 16);
  *(uint4*)(xb + i * 8) = o;
}

// ---------------- kernel 2: build Wt (640 x 224) bf16, zero padded -------
// Wt[n][k] = W[k][n], W = [wq | wk | wv] columns (n<200:wq, <400:wk, <600:wv)
__global__ __launch_bounds__(256) void build_wt_kernel(const float* __restrict__ wq,
                                                       const float* __restrict__ wk,
                                                       const float* __restrict__ wv,
                                                       unsigned short* __restrict__ wt) {
  int i = blockIdx.x * 256 + threadIdx.x;  // over 640*224
  int n = i / 224, k = i - n * 224;
  float val = 0.f;
  if (n < 600 && k < 200) {
    const float* src = (n < 200) ? wq : ((n < 400) ? wk : wv);
    val = src[k * 200 + (n % 200)];
  }
  wt[i] = f2b(val);
}

// ---------------- kernel 3/5: bf16 GEMM, C = A @ Wt^T ---------------------
// A: M x Astride bf16 (logical K=200; k in [200,224) reads junk, but Wt is 0 there)
// Bt: 640 x 224 bf16 (n-major)
// out: either Cb (bf16) or Cf (fp32), row stride Cstride, guard n < Ncols
__global__ __launch_bounds__(256) void gemm_kernel(
    const unsigned short* __restrict__ A, long Astride,
    const unsigned short* __restrict__ Bt,
    unsigned short* __restrict__ Cb, float* __restrict__ Cf,
    long Cstride, int Ncols) {
  __shared__ unsigned short sA[128 * 32];
  __shared__ unsigned short sB[128 * 32];
  int nb = blockIdx.x, mb = blockIdx.y;
  long mBase = (long)mb * 128;
  int nBase = nb * 128;
  int tid = threadIdx.x;
  int lane = tid & 63, w = tid >> 6;
  int wm = w & 1, wn = w >> 1;
  int frow = lane & 15, fk = (lane >> 4) * 8;

  f32x4 acc[4][4] = {};

  for (int kk = 0; kk < 7; ++kk) {
    int k0 = kk * 32;
    for (int i = 0; i < 2; ++i) {
      int chunk = i * 256 + w * 64 + lane;   // 16B chunk id within tile
      int row = chunk >> 2;
      int col = (chunk & 3) * 8;
      lds_load16(&sA[(i * 256 + w * 64) * 8], A + (mBase + row) * Astride + k0 + col);
      lds_load16(&sB[(i * 256 + w * 64) * 8], Bt + (long)(nBase + row) * 224 + k0 + col);
    }
    __syncthreads();
    bf16x8 fa[4], fb[4];
    for (int i = 0; i < 4; i++) fa[i] = *(const bf16x8*)&sA[(wm * 64 + i * 16 + frow) * 32 + fk];
    for (int j = 0; j < 4; j++) fb[j] = *(const bf16x8*)&sB[(wn * 64 + j * 16 + frow) * 32 + fk];
    for (int i = 0; i < 4; i++)
      for (int j = 0; j < 4; j++)
        acc[i][j] = __builtin_amdgcn_mfma_f32_16x16x32_bf16(fa[i], fb[j], acc[i][j], 0, 0, 0);
    __syncthreads();
  }

  int rbase = (lane >> 4) * 4;
  int cN = lane & 15;
  for (int i = 0; i < 4; i++)
    for (int j = 0; j < 4; j++) {
      int n = nBase + wn * 64 + j * 16 + cN;
      if (n < Ncols) {
        long rowg = mBase + wm * 64 + i * 16 + rbase;
        for (int r = 0; r < 4; r++) {
          long off = (rowg + r) * Cstride + n;
          if (Cb) Cb[off] = f2b(acc[i][j][r]);
          else Cf[off] = acc[i][j][r];
        }
      }
    }
}

// ---------------- kernel 4: fused attention per (bf, head) ----------------
// qkv: 131072 x 600 bf16.  attn_out: (1024,10,128,128) fp32.
// out_pre: 131072 x 200 bf16 (row = bf*128+s, col = h*20+d)
__global__ __launch_bounds__(256) void attn_kernel(
    const unsigned short* __restrict__ qkv,
    float* __restrict__ attn_out,
    unsigned short* __restrict__ out_pre) {
  __shared__ unsigned short sQ[128 * 32];   // [t][d] pad d to 32
  __shared__ unsigned short sK[128 * 32];   // [t'][d]
  __shared__ unsigned short sV[32 * 128];   // transposed: [d][t]
  __shared__ unsigned short sS[128 * 128];  // S (bf16) then P (bf16) in place

  int blk = blockIdx.x;
  int bf = blk / 10, h = blk - bf * 10;
  int tid = threadIdx.x, lane = tid & 63, w = tid >> 6;
  long rowBase = (long)bf * 128;

  // zero the padded staging buffers
  for (int i = tid; i < 128 * 32 / 2; i += 256) {
    ((unsigned*)sQ)[i] = 0; ((unsigned*)sK)[i] = 0; ((unsigned*)sV)[i] = 0;
  }
  __syncthreads();

  // stage q,k,v: 3 tiles x 128 rows x 5 chunks of 4 bf16
  for (int c = tid; c < 1920; c += 256) {
    int tile = c / 640;
    int rem = c - tile * 640;
    int row = rem / 5, j = rem - row * 5;
    const unsigned short* g = qkv + (rowBase + row) * 600 + tile * 200 + h * 20 + j * 4;
    ushort4 d = *(const ushort4*)g;
    if (tile < 2) {
      unsigned short* dst = (tile == 0 ? sQ : sK) + row * 32 + j * 4;
      *(ushort4*)dst = d;
    } else {
      sV[(j * 4 + 0) * 128 + row] = d.x;
      sV[(j * 4 + 1) * 128 + row] = d.y;
      sV[(j * 4 + 2) * 128 + row] = d.z;
      sV[(j * 4 + 3) * 128 + row] = d.w;
    }
  }
  __syncthreads();

  // S = (Q K^T) * scale  -- one 16x16x32 MFMA per tile pair (K padded to 32)
  int frow = lane & 15, fk = (lane >> 4) * 8;
  int wm = w & 1, wn = w >> 1;
  {
    bf16x8 qf[4], kf[4];
    for (int i = 0; i < 4; i++) qf[i] = *(const bf16x8*)&sQ[(wm * 64 + i * 16 + frow) * 32 + fk];
    for (int j = 0; j < 4; j++) kf[j] = *(const bf16x8*)&sK[(wn * 64 + j * 16 + frow) * 32 + fk];
    const float scale = 0.22360679774997896f;  // 1/sqrt(20)
    for (int i = 0; i < 4; i++)
      for (int j = 0; j < 4; j++) {
        f32x4 z = {0.f, 0.f, 0.f, 0.f};
        f32x4 s = __builtin_amdgcn_mfma_f32_16x16x32_bf16(qf[i], kf[j], z, 0, 0, 0);
        int srow = wm * 64 + i * 16 + (lane >> 4) * 4;
        int tcol = wn * 64 + j * 16 + (lane & 15);
        for (int r = 0; r < 4; r++) sS[(srow + r) * 128 + tcol] = f2b(s[r] * scale);
      }
  }
  __syncthreads();

  // row-wise softmax: wave w owns rows [32w, 32w+32); lane handles t=lane, t=lane+64
  long attnBase = (long)blk * 16384;
  for (int rr = 0; rr < 32; ++rr) {
    int r = w * 32 + rr;
    float x0 = b2f(sS[r * 128 + lane]);
    float x1 = b2f(sS[r * 128 + 64 + lane]);
    float m = fmaxf(x0, x1);
    for (int off = 32; off; off >>= 1) m = fmaxf(m, __shfl_xor(m, off, 64));
    float e0 = __expf(x0 - m), e1 = __expf(x1 - m);
    float s = e0 + e1;
    for (int off = 32; off; off >>= 1) s += __shfl_xor(s, off, 64);
    float inv = 1.0f / s;
    float w0 = e0 * inv, w1 = e1 * inv;
    attn_out[attnBase + (long)r * 128 + lane] = w0;
    attn_out[attnBase + (long)r * 128 + 64 + lane] = w1;
    sS[r * 128 + lane] = f2b(w0);
    sS[r * 128 + 64 + lane] = f2b(w1);
  }
  __syncthreads();

  // O = P @ V : wave w owns s-rows [32w, 32w+32); N=32 (d padded), K=128
  {
    f32x4 accO[2][2] = {};
    int m0 = w * 32;
    for (int ks = 0; ks < 4; ks++) {
      bf16x8 pf[2], vf[2];
      for (int i = 0; i < 2; i++)
        pf[i] = *(const bf16x8*)&sS[(m0 + i * 16 + frow) * 128 + ks * 32 + fk];
      for (int j = 0; j < 2; j++)
        vf[j] = *(const bf16x8*)&sV[(j * 16 + frow) * 128 + ks * 32 + fk];
      for (int i = 0; i < 2; i++)
        for (int j = 0; j < 2; j++)
          accO[i][j] = __builtin_amdgcn_mfma_f32_16x16x32_bf16(pf[i], vf[j], accO[i][j], 0, 0, 0);
    }
    for (int i = 0; i < 2; i++)
      for (int j = 0; j < 2; j++) {
        int d = j * 16 + (lane & 15);
        if (d < 20) {
          int srow = m0 + i * 16 + (lane >> 4) * 4;
          for (int r = 0; r < 4; r++)
            out_pre[(rowBase + srow + r) * 200 + h * 20 + d] = f2b(accO[i][j][r]);
        }
      }
  }
}

extern "C" void kernel_launch(void* const* d_in, const int* in_sizes, int n_in,
                              void* d_out, int out_size, void* d_ws, size_t ws_size,
                              hipStream_t stream) {
  const float* x  = (const float*)d_in[0];
  const float* wq = (const float*)d_in[1];
  const float* wk = (const float*)d_in[2];
  const float* wv = (const float*)d_in[3];
  float* out = (float*)d_out;

  char* ws = (char*)d_ws;
  // layout (bytes):
  //   xb / out_pre (aliased, temporally disjoint): 131072*200*2 = 52,428,800
  //   wt: 640*224*2 = 286,720
  //   qkv: 131072*600*2 = 157,286,400           total ~210 MB
  unsigned short* xb      = (unsigned short*)ws;
  unsigned short* wt      = (unsigned short*)(ws + 52428800);
  unsigned short* qkv     = (unsigned short*)(ws + 52428800 + 286720);
  unsigned short* out_pre = xb;  // reuse: xb dead after QKV GEMM

  // 1) convert x to bf16
  cvt_x_kernel<<<12800, 256, 0, stream>>>(x, xb);
  // 2) build packed transposed weights (serves QKV and final projection)
  build_wt_kernel<<<560, 256, 0, stream>>>(wq, wk, wv, wt);
  // 3) QKV projection: (131072 x 200) @ (200 x 600) -> qkv bf16
  gemm_kernel<<<dim3(5, 1024), 256, 0, stream>>>(xb, 200, wt, qkv, nullptr, 600, 600);
  // 4) fused attention: writes attn weights (fp32, d_out) + out_pre (bf16)
  attn_kernel<<<10240, 256, 0, stream>>>(qkv, out, out_pre);
  // 5) output projection: (131072 x 200) @ wq -> d_out second chunk (fp32)
  gemm_kernel<<<dim3(2, 1024), 256, 0, stream>>>(out_pre, 200, wt, nullptr,
                                                 out + 167772160L, 200, 200);
}